// Round 1
// baseline (1601.852 us; speedup 1.0000x reference)
//
#include <hip/hip_runtime.h>
#include <hip/hip_bf16.h>

#define NN 50000      // nodes
#define RO 5          // original relations
#define RT 11         // total relations (2*RO+1)
#define FF 128        // feature dim (in == out)
#define EE 800000     // edges

typedef unsigned short u16;
typedef __attribute__((ext_vector_type(4))) unsigned short u16x4;
typedef __attribute__((ext_vector_type(8))) short bf16x8;   // 8 bf16 (4 VGPRs)
typedef __attribute__((ext_vector_type(4))) float f32x4;

// fp32 -> bf16 round-to-nearest-even (values are finite/normal here)
__device__ __forceinline__ u16 f2b(float x) {
  unsigned u = __float_as_uint(x);
  unsigned r = (u + 0x7fffu + ((u >> 16) & 1u)) >> 16;
  return (u16)r;
}

// ---- cast features fp32 -> bf16 (vectorized, exact grid) ----
__global__ __launch_bounds__(256) void cast_feat_k(const float* __restrict__ f,
                                                   u16* __restrict__ fb) {
  int i = blockIdx.x * 256 + threadIdx.x;          // handles 4 floats
  float4 v = reinterpret_cast<const float4*>(f)[i];
  u16x4 o;
  o.x = f2b(v.x); o.y = f2b(v.y); o.z = f2b(v.z); o.w = f2b(v.w);
  reinterpret_cast<u16x4*>(fb)[i] = o;
}

// ---- transpose weights to Wt[r][o][k] bf16; fold root into r==10 ----
__global__ __launch_bounds__(256) void wt_k(const float* __restrict__ w,
                                            const float* __restrict__ root,
                                            u16* __restrict__ wt) {
  int idx = blockIdx.x * 256 + threadIdx.x;        // r*16384 + k*128 + o
  int r = idx >> 14;
  int rem = idx & 16383;
  int k = rem >> 7;
  int o = rem & 127;
  float v = w[idx];
  if (r == 10) v += root[rem];
  wt[(r << 14) + (o << 7) + k] = f2b(v);
}

// ---- per-(rel,dst) in-degree counts for r in [0,10) ----
__global__ __launch_bounds__(256) void count_k(const int* __restrict__ g,
                                               int* __restrict__ cnt) {
  int e = blockIdx.x * 256 + threadIdx.x;
  if (e >= EE) return;
  int s = g[3 * e], r = g[3 * e + 1], d = g[3 * e + 2];
  atomicAdd(&cnt[r * NN + d], 1);            // forward: rel, dst
  atomicAdd(&cnt[(r + RO) * NN + s], 1);     // reversed: rel+RO, src
}

// ---- batched GEMM: H[r] = fbf @ W_r (bf16 out) for r<10; out = fbf @ (W10+root) fp32 ----
// block = 256 (4 waves), each wave owns 16 rows x 128 cols; grid = (ceil(NN/64), 11)
__global__ __launch_bounds__(256) void gemm_k(const u16* __restrict__ fbf,
                                              const u16* __restrict__ wt,
                                              u16* __restrict__ H,
                                              float* __restrict__ out) {
  const int r    = blockIdx.y;
  const int lane = threadIdx.x & 63;
  const int wv   = threadIdx.x >> 6;
  const int l15  = lane & 15;
  const int ko   = lane >> 4;                 // 0..3 (k-subchunk of 8)
  const int row  = blockIdx.x * 64 + wv * 16 + l15;
  const bool inb = row < NN;
  const u16* wb  = wt + (r << 14);

  f32x4 acc[8];
#pragma unroll
  for (int i = 0; i < 8; ++i) acc[i] = (f32x4){0.f, 0.f, 0.f, 0.f};

#pragma unroll
  for (int kc = 0; kc < 4; ++kc) {
    bf16x8 a = {0, 0, 0, 0, 0, 0, 0, 0};
    if (inb) a = *reinterpret_cast<const bf16x8*>(fbf + row * FF + kc * 32 + ko * 8);
#pragma unroll
    for (int cf = 0; cf < 8; ++cf) {
      bf16x8 b = *reinterpret_cast<const bf16x8*>(wb + (cf * 16 + l15) * FF + kc * 32 + ko * 8);
      acc[cf] = __builtin_amdgcn_mfma_f32_16x16x32_bf16(a, b, acc[cf], 0, 0, 0);
    }
  }

  // D layout: col = lane&15, row = (lane>>4)*4 + reg  [guide §3, m89/m91]
  const int rbase = blockIdx.x * 64 + wv * 16 + ko * 4;
  if (r < 10) {
    u16* hb = H + (long)r * NN * FF;
#pragma unroll
    for (int cf = 0; cf < 8; ++cf)
#pragma unroll
      for (int q = 0; q < 4; ++q) {
        int rd = rbase + q;
        if (rd < NN) hb[rd * FF + cf * 16 + l15] = f2b(acc[cf][q]);
      }
  } else {
#pragma unroll
    for (int cf = 0; cf < 8; ++cf)
#pragma unroll
      for (int q = 0; q < 4; ++q) {
        int rd = rbase + q;
        if (rd < NN) out[rd * FF + cf * 16 + l15] = acc[cf][q];
      }
  }
}

// ---- scatter: one wave per edge-message; out[dst] += H[r][src] / cnt[r][dst] ----
__global__ __launch_bounds__(256) void scatter_k(const int* __restrict__ g,
                                                 const u16* __restrict__ H,
                                                 const int* __restrict__ cnt,
                                                 float* __restrict__ out) {
  const int m = blockIdx.x * 4 + (threadIdx.x >> 6);   // message id, 2E exact
  const int lane = threadIdx.x & 63;
  int e, r, sn, dn;
  if (m < EE) { e = m;      sn = g[3 * e]; r = g[3 * e + 1];      dn = g[3 * e + 2]; }
  else        { e = m - EE; dn = g[3 * e]; r = g[3 * e + 1] + RO; sn = g[3 * e + 2]; }
  const float inv = 1.0f / (float)cnt[r * NN + dn];
  const unsigned pair = reinterpret_cast<const unsigned*>(H + ((long)r * NN + sn) * FF)[lane];
  const float v0 = __uint_as_float(pair << 16) * inv;          // low bf16
  const float v1 = __uint_as_float(pair & 0xffff0000u) * inv;  // high bf16
  float* orow = out + (long)dn * FF + lane * 2;
  atomicAdd(orow, v0);
  atomicAdd(orow + 1, v1);
}

extern "C" void kernel_launch(void* const* d_in, const int* in_sizes, int n_in,
                              void* d_out, int out_size, void* d_ws, size_t ws_size,
                              hipStream_t stream) {
  const int*   graph  = (const int*)d_in[0];
  const float* feat   = (const float*)d_in[1];
  const float* weight = (const float*)d_in[2];
  const float* root   = (const float*)d_in[3];
  float* out = (float*)d_out;
  char* ws = (char*)d_ws;

  // workspace layout (256B-aligned): fbf | Wt | cnt | H  -> ~143 MB total
  u16* fbf = (u16*)(ws);                       // 50000*128*2    = 12,800,000
  u16* wt  = (u16*)(ws + 12800000);            // 11*128*128*2   =    360,448
  int* cnt = (int*)(ws + 13160448);            // 10*50000*4     =  2,000,000 (+pad)
  u16* H   = (u16*)(ws + 15160576);            // 10*50000*128*2 = 128,000,000

  hipMemsetAsync(cnt, 0, 10 * NN * sizeof(int), stream);
  count_k<<<(EE + 255) / 256, 256, 0, stream>>>(graph, cnt);
  cast_feat_k<<<(NN * FF / 4) / 256, 256, 0, stream>>>(feat, fbf);
  wt_k<<<(RT * FF * FF) / 256, 256, 0, stream>>>(weight, root, wt);
  gemm_k<<<dim3((NN + 63) / 64, RT), 256, 0, stream>>>(fbf, wt, H, out);
  scatter_k<<<(2 * EE) / 4, 256, 0, stream>>>(graph, H, cnt, out);
}

// Round 2
// 629.188 us; speedup vs baseline: 2.5459x; 2.5459x over previous
//
#include <hip/hip_runtime.h>
#include <hip/hip_bf16.h>

#define NN 50000      // nodes
#define RO 5          // original relations
#define RT 11         // total relations (2*RO+1)
#define FF 128        // feature dim (in == out)
#define EE 800000     // edges
#define NBINS (2 * RO * NN)          // 500000 segment bins (r<10)
#define NBLK ((NBINS + 255) / 256)   // 1954 scan blocks

typedef unsigned short u16;
typedef unsigned int u32;
typedef __attribute__((ext_vector_type(4))) unsigned short u16x4;
typedef __attribute__((ext_vector_type(8))) short bf16x8;   // 8 bf16 (4 VGPRs)
typedef __attribute__((ext_vector_type(4))) float f32x4;

// fp32 -> bf16 round-to-nearest-even
__device__ __forceinline__ u16 f2b(float x) {
  unsigned u = __float_as_uint(x);
  return (u16)((u + 0x7fffu + ((u >> 16) & 1u)) >> 16);
}

// ---- cast features fp32 -> bf16 (vectorized, exact grid) ----
__global__ __launch_bounds__(256) void cast_feat_k(const float* __restrict__ f,
                                                   u16* __restrict__ fb) {
  int i = blockIdx.x * 256 + threadIdx.x;          // 4 floats per thread
  float4 v = reinterpret_cast<const float4*>(f)[i];
  u16x4 o;
  o.x = f2b(v.x); o.y = f2b(v.y); o.z = f2b(v.z); o.w = f2b(v.w);
  reinterpret_cast<u16x4*>(fb)[i] = o;
}

// ---- transpose weights to Wt[r][o][k] bf16; fold root into r==10 ----
__global__ __launch_bounds__(256) void wt_k(const float* __restrict__ w,
                                            const float* __restrict__ root,
                                            u16* __restrict__ wt) {
  int idx = blockIdx.x * 256 + threadIdx.x;        // r*16384 + k*128 + o
  int r = idx >> 14;
  int rem = idx & 16383;
  int k = rem >> 7;
  int o = rem & 127;
  float v = w[idx];
  if (r == 10) v += root[rem];
  wt[(r << 14) + (o << 7) + k] = f2b(v);
}

// ---- per-(rel,dst) in-degree counts for r in [0,10) ----
__global__ __launch_bounds__(256) void count_k(const int* __restrict__ g,
                                               int* __restrict__ cnt) {
  int e = blockIdx.x * 256 + threadIdx.x;          // grid exact: EE/256
  int s = g[3 * e], r = g[3 * e + 1], d = g[3 * e + 2];
  atomicAdd(&cnt[r * NN + d], 1);            // forward: rel, dst
  atomicAdd(&cnt[(r + RO) * NN + s], 1);     // reversed: rel+RO, src
}

// ---- scan pass 1: per-block exclusive scan (in place) + block totals ----
__global__ __launch_bounds__(256) void scan1_k(int* __restrict__ cnt,
                                               int* __restrict__ bsum) {
  __shared__ int sm[256];
  int g = blockIdx.x * 256 + threadIdx.x;
  int v = (g < NBINS) ? cnt[g] : 0;
  sm[threadIdx.x] = v;
  __syncthreads();
#pragma unroll
  for (int o = 1; o < 256; o <<= 1) {
    int t = (threadIdx.x >= o) ? sm[threadIdx.x - o] : 0;
    __syncthreads();
    sm[threadIdx.x] += t;
    __syncthreads();
  }
  if (g < NBINS) cnt[g] = sm[threadIdx.x] - v;     // exclusive within block
  if (threadIdx.x == 255) bsum[blockIdx.x] = sm[255];
}

// ---- scan pass 2: single-block exclusive scan of block totals ----
__global__ __launch_bounds__(256) void scan2_k(int* __restrict__ bsum) {
  __shared__ int sm[256];
  __shared__ int carry;
  if (threadIdx.x == 0) carry = 0;
  __syncthreads();
  for (int base = 0; base < NBLK; base += 256) {
    int g = base + threadIdx.x;
    int v = (g < NBLK) ? bsum[g] : 0;
    sm[threadIdx.x] = v;
    __syncthreads();
#pragma unroll
    for (int o = 1; o < 256; o <<= 1) {
      int t = (threadIdx.x >= o) ? sm[threadIdx.x - o] : 0;
      __syncthreads();
      sm[threadIdx.x] += t;
      __syncthreads();
    }
    int excl = sm[threadIdx.x] - v + carry;
    if (g < NBLK) bsum[g] = excl;
    __syncthreads();
    if (threadIdx.x == 255) carry = excl + v;
    __syncthreads();
  }
}

// ---- fill CSR edge lists ----
__global__ __launch_bounds__(256) void fill_k(const int* __restrict__ g,
                                              const int* __restrict__ loc,
                                              const int* __restrict__ bsum,
                                              int* __restrict__ cur,
                                              int* __restrict__ eidx) {
  int m = blockIdx.x * 256 + threadIdx.x;          // grid exact: 2*EE/256
  int e, r, sn, dn;
  if (m < EE) { e = m;      sn = g[3 * e]; r = g[3 * e + 1];      dn = g[3 * e + 2]; }
  else        { e = m - EE; dn = g[3 * e]; r = g[3 * e + 1] + RO; sn = g[3 * e + 2]; }
  int bin = r * NN + dn;
  int pos = loc[bin] + bsum[bin >> 8] + atomicAdd(&cur[bin], 1);
  eidx[pos] = sn;
}

// ---- segment mean: one wave per (r,dst) bin, no atomics ----
__global__ __launch_bounds__(256) void mean_k(const int* __restrict__ cnt,
                                              const int* __restrict__ loc,
                                              const int* __restrict__ bsum,
                                              const int* __restrict__ eidx,
                                              const u32* __restrict__ fv,
                                              u32* __restrict__ Mv) {
  int seg = blockIdx.x * 4 + (threadIdx.x >> 6);   // grid exact: NBINS/4
  int lane = threadIdx.x & 63;
  int c = cnt[seg];
  int start = loc[seg] + bsum[seg >> 8];
  float a0 = 0.f, a1 = 0.f;
  for (int i = 0; i < c; ++i) {
    int s = eidx[start + i];
    u32 p = fv[s * 64 + lane];
    a0 += __uint_as_float(p << 16);
    a1 += __uint_as_float(p & 0xffff0000u);
  }
  float inv = 1.0f / (float)(c > 0 ? c : 1);
  u32 pk = (u32)f2b(a0 * inv) | ((u32)f2b(a1 * inv) << 16);
  Mv[(long)seg * 64 + lane] = pk;
}

// ---- fused GEMM: out = sum_r M_r @ W_r + f @ (W10+root), K = 11*128 ----
// block = 256 (4 waves), each wave: 16 rows x 128 cols; grid = ceil(NN/64)
__global__ __launch_bounds__(256) void gemm2_k(const u16* __restrict__ fbf,
                                               const u16* __restrict__ M,
                                               const u16* __restrict__ wt,
                                               float* __restrict__ out) {
  const int lane = threadIdx.x & 63;
  const int wv   = threadIdx.x >> 6;
  const int l15  = lane & 15;
  const int ko   = lane >> 4;                 // 0..3 (k-subchunk of 8)
  const int row  = blockIdx.x * 64 + wv * 16 + l15;
  const bool inb = row < NN;
  const int rowc = inb ? row : 0;

  f32x4 acc[8];
#pragma unroll
  for (int i = 0; i < 8; ++i) acc[i] = (f32x4){0.f, 0.f, 0.f, 0.f};

#pragma unroll
  for (int r = 0; r < RT; ++r) {
    const u16* arow = (r < 10) ? (M + ((long)r * NN + rowc) * FF)
                               : (fbf + (long)rowc * FF);
    const u16* wb = wt + (r << 14);
#pragma unroll
    for (int kc = 0; kc < 4; ++kc) {
      bf16x8 a = {0, 0, 0, 0, 0, 0, 0, 0};
      if (inb) a = *reinterpret_cast<const bf16x8*>(arow + kc * 32 + ko * 8);
#pragma unroll
      for (int cf = 0; cf < 8; ++cf) {
        bf16x8 b = *reinterpret_cast<const bf16x8*>(wb + (cf * 16 + l15) * FF + kc * 32 + ko * 8);
        acc[cf] = __builtin_amdgcn_mfma_f32_16x16x32_bf16(a, b, acc[cf], 0, 0, 0);
      }
    }
  }

  // D layout: col = lane&15, row = (lane>>4)*4 + reg  [guide §3, m89/m91]
  const int rbase = blockIdx.x * 64 + wv * 16 + ko * 4;
#pragma unroll
  for (int cf = 0; cf < 8; ++cf)
#pragma unroll
    for (int q = 0; q < 4; ++q) {
      int rd = rbase + q;
      if (rd < NN) out[rd * FF + cf * 16 + l15] = acc[cf][q];
    }
}

extern "C" void kernel_launch(void* const* d_in, const int* in_sizes, int n_in,
                              void* d_out, int out_size, void* d_ws, size_t ws_size,
                              hipStream_t stream) {
  const int*   graph  = (const int*)d_in[0];
  const float* feat   = (const float*)d_in[1];
  const float* weight = (const float*)d_in[2];
  const float* root   = (const float*)d_in[3];
  float* out = (float*)d_out;
  char* ws = (char*)d_ws;

  // workspace layout (all 256B-aligned), ~152 MB total:
  u16* fbf  = (u16*)(ws);                       // 50000*128*2    = 12,800,000
  u16* wt   = (u16*)(ws + 12800000);            // 11*128*128*2   =    360,448
  int* cnt  = (int*)(ws + 13160448);            // NBINS*4        =  2,000,000  (counts -> in-place local excl scan)
  int* cur  = (int*)(ws + 15160448);            // NBINS*4        =  2,000,000  (fill cursors; == counts after fill)
  int* bsum = (int*)(ws + 17160448);            // NBLK*4 (pad)   =      8,192
  int* eidx = (int*)(ws + 17168640);            // 2*EE*4         =  6,400,000
  u16* M    = (u16*)(ws + 23568640);            // 10*50000*128*2 = 128,000,000

  hipMemsetAsync(cnt, 0, NBINS * sizeof(int), stream);
  hipMemsetAsync(cur, 0, NBINS * sizeof(int), stream);
  cast_feat_k<<<(NN * FF / 4) / 256, 256, 0, stream>>>(feat, fbf);
  wt_k<<<(RT * FF * FF) / 256, 256, 0, stream>>>(weight, root, wt);
  count_k<<<EE / 256, 256, 0, stream>>>(graph, cnt);
  scan1_k<<<NBLK, 256, 0, stream>>>(cnt, bsum);
  scan2_k<<<1, 256, 0, stream>>>(bsum);
  fill_k<<<2 * EE / 256, 256, 0, stream>>>(graph, cnt, bsum, cur, eidx);
  mean_k<<<NBINS / 4, 256, 0, stream>>>(cur, cnt, bsum, eidx, (const u32*)fbf, (u32*)M);
  gemm2_k<<<(NN + 63) / 64, 256, 0, stream>>>(fbf, M, wt, out);
}

// Round 3
// 602.225 us; speedup vs baseline: 2.6599x; 1.0448x over previous
//
#include <hip/hip_runtime.h>
#include <hip/hip_bf16.h>

#define NN 50000      // nodes
#define RO 5          // original relations
#define RT 11         // total relations (2*RO+1)
#define FF 128        // feature dim (in == out)
#define EE 800000     // edges
#define NBINS (2 * RO * NN)          // 500000 segment bins (r<10)
#define NBLK ((NBINS + 255) / 256)   // 1954 scan blocks

typedef unsigned short u16;
typedef unsigned int u32;
typedef __attribute__((ext_vector_type(4))) unsigned short u16x4;
typedef __attribute__((ext_vector_type(8))) short bf16x8;   // 8 bf16 (4 VGPRs)
typedef __attribute__((ext_vector_type(4))) float f32x4;

// fp32 -> bf16 round-to-nearest-even
__device__ __forceinline__ u16 f2b(float x) {
  unsigned u = __float_as_uint(x);
  return (u16)((u + 0x7fffu + ((u >> 16) & 1u)) >> 16);
}

// ---- prep: cast features fp32->bf16  +  transpose weights (root folded into r=10) ----
__global__ __launch_bounds__(256) void prep_k(const float* __restrict__ f,
                                              const float* __restrict__ w,
                                              const float* __restrict__ root,
                                              u16* __restrict__ fb,
                                              u16* __restrict__ wt) {
  int b = blockIdx.x;
  if (b < (NN * FF / 4) / 256) {                   // 6250 feature blocks, 4 floats/thread
    int i = b * 256 + threadIdx.x;
    float4 v = reinterpret_cast<const float4*>(f)[i];
    u16x4 o;
    o.x = f2b(v.x); o.y = f2b(v.y); o.z = f2b(v.z); o.w = f2b(v.w);
    reinterpret_cast<u16x4*>(fb)[i] = o;
  } else {                                         // 704 weight blocks
    int idx = (b - (NN * FF / 4) / 256) * 256 + threadIdx.x;  // r*16384 + k*128 + o
    int r = idx >> 14;
    int rem = idx & 16383;
    int k = rem >> 7;
    int o = rem & 127;
    float v = w[idx];
    if (r == 10) v += root[rem];
    wt[(r << 14) + (o << 7) + k] = f2b(v);
  }
}

// ---- per-(rel,dst) in-degree counts for r in [0,10) ----
__global__ __launch_bounds__(256) void count_k(const int* __restrict__ g,
                                               int* __restrict__ cnt) {
  int e = blockIdx.x * 256 + threadIdx.x;          // grid exact: EE/256
  int s = g[3 * e], r = g[3 * e + 1], d = g[3 * e + 2];
  atomicAdd(&cnt[r * NN + d], 1);            // forward: rel, dst
  atomicAdd(&cnt[(r + RO) * NN + s], 1);     // reversed: rel+RO, src
}

// ---- scan pass 1: per-block exclusive scan (in place) + block totals ----
__global__ __launch_bounds__(256) void scan1_k(int* __restrict__ cnt,
                                               int* __restrict__ bsum) {
  __shared__ int sm[256];
  int g = blockIdx.x * 256 + threadIdx.x;
  int v = (g < NBINS) ? cnt[g] : 0;
  sm[threadIdx.x] = v;
  __syncthreads();
#pragma unroll
  for (int o = 1; o < 256; o <<= 1) {
    int t = (threadIdx.x >= o) ? sm[threadIdx.x - o] : 0;
    __syncthreads();
    sm[threadIdx.x] += t;
    __syncthreads();
  }
  if (g < NBINS) cnt[g] = sm[threadIdx.x] - v;     // exclusive within block
  if (threadIdx.x == 255) bsum[blockIdx.x] = sm[255];
}

// ---- scan pass 2: single-block exclusive scan of block totals ----
__global__ __launch_bounds__(256) void scan2_k(int* __restrict__ bsum) {
  __shared__ int sm[256];
  __shared__ int carry;
  if (threadIdx.x == 0) carry = 0;
  __syncthreads();
  for (int base = 0; base < NBLK; base += 256) {
    int g = base + threadIdx.x;
    int v = (g < NBLK) ? bsum[g] : 0;
    sm[threadIdx.x] = v;
    __syncthreads();
#pragma unroll
    for (int o = 1; o < 256; o <<= 1) {
      int t = (threadIdx.x >= o) ? sm[threadIdx.x - o] : 0;
      __syncthreads();
      sm[threadIdx.x] += t;
      __syncthreads();
    }
    int excl = sm[threadIdx.x] - v + carry;
    if (g < NBLK) bsum[g] = excl;
    __syncthreads();
    if (threadIdx.x == 255) carry = excl + v;
    __syncthreads();
  }
}

// ---- fill CSR edge lists ----
__global__ __launch_bounds__(256) void fill_k(const int* __restrict__ g,
                                              const int* __restrict__ loc,
                                              const int* __restrict__ bsum,
                                              int* __restrict__ cur,
                                              int* __restrict__ eidx) {
  int m = blockIdx.x * 256 + threadIdx.x;          // grid exact: 2*EE/256
  int e, r, sn, dn;
  if (m < EE) { e = m;      sn = g[3 * e]; r = g[3 * e + 1];      dn = g[3 * e + 2]; }
  else        { e = m - EE; dn = g[3 * e]; r = g[3 * e + 1] + RO; sn = g[3 * e + 2]; }
  int bin = r * NN + dn;
  int pos = loc[bin] + bsum[bin >> 8] + atomicAdd(&cur[bin], 1);
  eidx[pos] = sn;
}

// ---- fused segment-mean + GEMM ----
// block = 256 (4 waves). Block owns 64 output rows; wave wv owns rows wv*16..+15.
// Per r<10: wave builds its 16-row mean tile in LDS (wave-local -> NO barriers),
// then MFMAs it against Wt_r. r==10 uses fbf from global. Single out write.
__global__ __launch_bounds__(256) void fused_k(const int* __restrict__ cnt,
                                               const int* __restrict__ loc,
                                               const int* __restrict__ bsum,
                                               const int* __restrict__ eidx,
                                               const u32* __restrict__ fv,
                                               const u16* __restrict__ fbf,
                                               const u16* __restrict__ wt,
                                               float* __restrict__ out) {
  __shared__ __align__(16) u32 tile[64 * 64];      // 16 KB, word-swizzled
  const int lane = threadIdx.x & 63;
  const int wv   = threadIdx.x >> 6;
  const int l15  = lane & 15;
  const int ko   = lane >> 4;                      // 0..3
  const int arow = wv * 16 + l15;                  // A-tile row this lane reads

  f32x4 acc[8];
#pragma unroll
  for (int i = 0; i < 8; ++i) acc[i] = (f32x4){0.f, 0.f, 0.f, 0.f};

  for (int r = 0; r < 10; ++r) {
    // ---- build 16-row mean tile (wave-local) ----
    for (int j = 0; j < 16; ++j) {
      const int rowloc = wv * 16 + j;
      const int n = blockIdx.x * 64 + rowloc;
      float a0 = 0.f, a1 = 0.f;
      if (n < NN) {
        const int seg = r * NN + n;
        const int c = cnt[seg];
        const int start = loc[seg] + bsum[seg >> 8];
        for (int base = 0; base < c; base += 64) {
          int m = c - base; if (m > 64) m = 64;
          int sv = (lane < m) ? eidx[start + base + lane] : 0;
          int i = 0;
          for (; i + 3 < m; i += 4) {              // 4 gathers in flight
            int s0 = __shfl(sv, i);
            int s1 = __shfl(sv, i + 1);
            int s2 = __shfl(sv, i + 2);
            int s3 = __shfl(sv, i + 3);
            u32 p0 = fv[s0 * 64 + lane];
            u32 p1 = fv[s1 * 64 + lane];
            u32 p2 = fv[s2 * 64 + lane];
            u32 p3 = fv[s3 * 64 + lane];
            a0 += __uint_as_float(p0 << 16) + __uint_as_float(p1 << 16)
                + __uint_as_float(p2 << 16) + __uint_as_float(p3 << 16);
            a1 += __uint_as_float(p0 & 0xffff0000u) + __uint_as_float(p1 & 0xffff0000u)
                + __uint_as_float(p2 & 0xffff0000u) + __uint_as_float(p3 & 0xffff0000u);
          }
          for (; i < m; ++i) {
            int s = __shfl(sv, i);
            u32 p = fv[s * 64 + lane];
            a0 += __uint_as_float(p << 16);
            a1 += __uint_as_float(p & 0xffff0000u);
          }
        }
        const float inv = (c > 0) ? 1.0f / (float)c : 0.f;
        a0 *= inv; a1 *= inv;
      }
      const u32 pk = (u32)f2b(a0) | ((u32)f2b(a1) << 16);
      tile[rowloc * 64 + (lane ^ ((rowloc & 7) << 2))] = pk;   // swizzled write
    }
    // ---- MFMA this relation (reads only rows this wave wrote) ----
    const u16* wb = wt + (r << 14);
#pragma unroll
    for (int kc = 0; kc < 4; ++kc) {
      const int w = (kc * 16 + ko * 4) ^ ((arow & 7) << 2);
      bf16x8 a = *reinterpret_cast<const bf16x8*>(&tile[arow * 64 + w]);
#pragma unroll
      for (int cf = 0; cf < 8; ++cf) {
        bf16x8 b = *reinterpret_cast<const bf16x8*>(wb + (cf * 16 + l15) * FF + kc * 32 + ko * 8);
        acc[cf] = __builtin_amdgcn_mfma_f32_16x16x32_bf16(a, b, acc[cf], 0, 0, 0);
      }
    }
  }

  // ---- r == 10: A = features (root folded into Wt[10]) ----
  {
    const int row = blockIdx.x * 64 + arow;
    const bool inb = row < NN;
    const int rowc = inb ? row : 0;
    const u16* wb = wt + (10 << 14);
#pragma unroll
    for (int kc = 0; kc < 4; ++kc) {
      bf16x8 a = {0, 0, 0, 0, 0, 0, 0, 0};
      if (inb) a = *reinterpret_cast<const bf16x8*>(fbf + (long)rowc * FF + kc * 32 + ko * 8);
#pragma unroll
      for (int cf = 0; cf < 8; ++cf) {
        bf16x8 b = *reinterpret_cast<const bf16x8*>(wb + (cf * 16 + l15) * FF + kc * 32 + ko * 8);
        acc[cf] = __builtin_amdgcn_mfma_f32_16x16x32_bf16(a, b, acc[cf], 0, 0, 0);
      }
    }
  }

  // ---- store: D layout col=lane&15, row=(lane>>4)*4+reg ----
  const int rbase = blockIdx.x * 64 + wv * 16 + ko * 4;
#pragma unroll
  for (int cf = 0; cf < 8; ++cf)
#pragma unroll
    for (int q = 0; q < 4; ++q) {
      int rd = rbase + q;
      if (rd < NN) out[rd * FF + cf * 16 + l15] = acc[cf][q];
    }
}

extern "C" void kernel_launch(void* const* d_in, const int* in_sizes, int n_in,
                              void* d_out, int out_size, void* d_ws, size_t ws_size,
                              hipStream_t stream) {
  const int*   graph  = (const int*)d_in[0];
  const float* feat   = (const float*)d_in[1];
  const float* weight = (const float*)d_in[2];
  const float* root   = (const float*)d_in[3];
  float* out = (float*)d_out;
  char* ws = (char*)d_ws;

  // workspace layout (256B-aligned), ~23.6 MB total:
  u16* fbf  = (u16*)(ws);                       // 50000*128*2  = 12,800,000
  u16* wt   = (u16*)(ws + 12800000);            // 11*128*128*2 =    360,448
  int* cnt  = (int*)(ws + 13160448);            // NBINS*4      =  2,000,000 (counts -> local excl scan in place)
  int* cur  = (int*)(ws + 15160448);            // NBINS*4      =  2,000,000 (fill cursors == counts after fill)
  int* bsum = (int*)(ws + 17160448);            // NBLK*4 (pad) =      8,192
  int* eidx = (int*)(ws + 17168640);            // 2*EE*4       =  6,400,000

  hipMemsetAsync(cnt, 0, NBINS * sizeof(int), stream);
  hipMemsetAsync(cur, 0, NBINS * sizeof(int), stream);
  prep_k<<<(NN * FF / 4) / 256 + (RT * FF * FF) / 256, 256, 0, stream>>>(feat, weight, root, fbf, wt);
  count_k<<<EE / 256, 256, 0, stream>>>(graph, cnt);
  scan1_k<<<NBLK, 256, 0, stream>>>(cnt, bsum);
  scan2_k<<<1, 256, 0, stream>>>(bsum);
  fill_k<<<2 * EE / 256, 256, 0, stream>>>(graph, cnt, bsum, cur, eidx);
  // fused: cnt=counts (cur), loc=scanned-local (cnt), bsum=block offsets
  fused_k<<<(NN + 63) / 64, 256, 0, stream>>>(cur, cnt, bsum, eidx,
                                              (const u32*)fbf, fbf, wt, out);
}

// Round 5
// 353.914 us; speedup vs baseline: 4.5261x; 1.7016x over previous
//
#include <hip/hip_runtime.h>
#include <hip/hip_bf16.h>

#define NN 50000      // nodes
#define RO 5          // original relations
#define RT 11         // total relations (2*RO+1)
#define FF 128        // feature dim (in == out)
#define EE 800000     // edges
#define EE2 (2 * EE)
#define NBINS (2 * RO * NN)          // 500000 segment bins (r<10)
#define NBLK ((NBINS + 255) / 256)   // 1954 scan blocks
#define FEAT_BLKS ((NN * FF / 4) / 256)   // 6250
#define WT_BLKS ((RT * FF * FF) / 256)    // 704

typedef unsigned short u16;
typedef unsigned int u32;
typedef __attribute__((ext_vector_type(4))) unsigned short u16x4;
typedef __attribute__((ext_vector_type(4))) unsigned int u32x4;
typedef __attribute__((ext_vector_type(8))) short bf16x8;   // 8 bf16 (4 VGPRs)
typedef __attribute__((ext_vector_type(4))) float f32x4;

// fp32 -> bf16 round-to-nearest-even
__device__ __forceinline__ u16 f2b(float x) {
  unsigned u = __float_as_uint(x);
  return (u16)((u + 0x7fffu + ((u >> 16) & 1u)) >> 16);
}

// ---- prep: cast features fp32->bf16 (+ zero row NN) + transpose/swizzle weights ----
// Weight layout: wt[r][o][chunk^(o&7)][k&7], chunk = k>>3 (16B-granular XOR swizzle
// so a LINEAR copy into LDS + swizzled ds_read_b128 is bank-conflict-free, rule 21).
__global__ __launch_bounds__(256) void prep_k(const float* __restrict__ f,
                                              const float* __restrict__ w,
                                              const float* __restrict__ root,
                                              u16* __restrict__ fb,
                                              u16* __restrict__ wt) {
  int b = blockIdx.x;
  if (b < FEAT_BLKS) {                             // features: 4 floats/thread
    int i = b * 256 + threadIdx.x;
    float4 v = reinterpret_cast<const float4*>(f)[i];
    u16x4 o;
    o.x = f2b(v.x); o.y = f2b(v.y); o.z = f2b(v.z); o.w = f2b(v.w);
    reinterpret_cast<u16x4*>(fb)[i] = o;
  } else if (b < FEAT_BLKS + WT_BLKS) {            // weights
    int idx = (b - FEAT_BLKS) * 256 + threadIdx.x; // r*16384 + k*128 + o
    int r = idx >> 14;
    int rem = idx & 16383;
    int k = rem >> 7;
    int o = rem & 127;
    float v = w[idx];
    if (r == 10) v += root[rem];
    int chunk = (k >> 3) ^ (o & 7);
    wt[(r << 14) + (o << 7) + (chunk << 3) + (k & 7)] = f2b(v);
  } else {                                         // zero row at index NN
    if (threadIdx.x < 64) reinterpret_cast<u32*>(fb)[NN * 64 + threadIdx.x] = 0;
  }
}

// ---- per-(rel,dst) in-degree counts for r in [0,10) ----
__global__ __launch_bounds__(256) void count_k(const int* __restrict__ g,
                                               int* __restrict__ cnt) {
  int e = blockIdx.x * 256 + threadIdx.x;          // grid exact: EE/256
  int s = g[3 * e], r = g[3 * e + 1], d = g[3 * e + 2];
  atomicAdd(&cnt[r * NN + d], 1);            // forward: rel, dst
  atomicAdd(&cnt[(r + RO) * NN + s], 1);     // reversed: rel+RO, src
}

// ---- scan pass 1: per-block exclusive scan (in place) + block totals ----
__global__ __launch_bounds__(256) void scan1_k(int* __restrict__ cnt,
                                               int* __restrict__ bsum) {
  __shared__ int sm[256];
  int g = blockIdx.x * 256 + threadIdx.x;
  int v = (g < NBINS) ? cnt[g] : 0;
  sm[threadIdx.x] = v;
  __syncthreads();
#pragma unroll
  for (int o = 1; o < 256; o <<= 1) {
    int t = (threadIdx.x >= o) ? sm[threadIdx.x - o] : 0;
    __syncthreads();
    sm[threadIdx.x] += t;
    __syncthreads();
  }
  if (g < NBINS) cnt[g] = sm[threadIdx.x] - v;     // exclusive within block
  if (threadIdx.x == 255) bsum[blockIdx.x] = sm[255];
}

// ---- scan pass 2: single-block exclusive scan of block totals ----
__global__ __launch_bounds__(256) void scan2_k(int* __restrict__ bsum) {
  __shared__ int sm[256];
  __shared__ int carry;
  if (threadIdx.x == 0) carry = 0;
  __syncthreads();
  for (int base = 0; base < NBLK; base += 256) {
    int g = base + threadIdx.x;
    int v = (g < NBLK) ? bsum[g] : 0;
    sm[threadIdx.x] = v;
    __syncthreads();
#pragma unroll
    for (int o = 1; o < 256; o <<= 1) {
      int t = (threadIdx.x >= o) ? sm[threadIdx.x - o] : 0;
      __syncthreads();
      sm[threadIdx.x] += t;
      __syncthreads();
    }
    int excl = sm[threadIdx.x] - v + carry;
    if (g < NBLK) bsum[g] = excl;
    __syncthreads();
    if (threadIdx.x == 255) carry = excl + v;
    __syncthreads();
  }
}

// ---- fill CSR edge lists (cur ends equal to counts; reused by mean_k) ----
__global__ __launch_bounds__(256) void fill_k(const int* __restrict__ g,
                                              const int* __restrict__ loc,
                                              const int* __restrict__ bsum,
                                              int* __restrict__ cur,
                                              int* __restrict__ eidx) {
  int m = blockIdx.x * 256 + threadIdx.x;          // grid exact: 2*EE/256
  int e, r, sn, dn;
  if (m < EE) { e = m;      sn = g[3 * e]; r = g[3 * e + 1];      dn = g[3 * e + 2]; }
  else        { e = m - EE; dn = g[3 * e]; r = g[3 * e + 1] + RO; sn = g[3 * e + 2]; }
  int bin = r * NN + dn;
  int pos = loc[bin] + bsum[bin >> 8] + atomicAdd(&cur[bin], 1);
  eidx[pos] = sn;
}

#define ACC(p) { a0 += __uint_as_float((p).x << 16); a1 += __uint_as_float((p).x & 0xffff0000u); \
                 a2 += __uint_as_float((p).y << 16); a3 += __uint_as_float((p).y & 0xffff0000u); \
                 a4 += __uint_as_float((p).z << 16); a5 += __uint_as_float((p).z & 0xffff0000u); \
                 a6 += __uint_as_float((p).w << 16); a7 += __uint_as_float((p).w & 0xffff0000u); }

// ---- segment mean: each 16-lane quarter-wave owns one (r,dst) bin ----
// 4 independent gather chains per wave + 4x unroll -> ~16 loads in flight.
// Branchless: invalid edges clamp to the zeroed feature row NN.
__global__ __launch_bounds__(256) void mean_k(const int* __restrict__ cnt,
                                              const int* __restrict__ loc,
                                              const int* __restrict__ bsum,
                                              const int* __restrict__ eidx,
                                              const u32x4* __restrict__ fv4,
                                              u32x4* __restrict__ Mv4) {
  const int lane = threadIdx.x & 63;
  const int wv   = threadIdx.x >> 6;
  const int q    = lane >> 4;
  const int l15  = lane & 15;
  const int q16  = q << 4;
  const int seg  = blockIdx.x * 16 + wv * 4 + q;   // grid exact: NBINS/16
  const int c     = cnt[seg];
  const int start = loc[seg] + bsum[seg >> 8];

  int cmax = c;
  cmax = max(cmax, __shfl_xor(cmax, 16));
  cmax = max(cmax, __shfl_xor(cmax, 32));          // wave-uniform max count

  float a0 = 0.f, a1 = 0.f, a2 = 0.f, a3 = 0.f, a4 = 0.f, a5 = 0.f, a6 = 0.f, a7 = 0.f;

  for (int base = 0; base < cmax; base += 16) {
    const int m = c - base;                        // valid edges this chunk (per quarter)
    int eaddr = start + base + l15;
    eaddr = min(eaddr, EE2 - 1);                   // OOB-safe (value unused when invalid)
    const int ei = eidx[eaddr];
    const int lim = min(cmax - base, 16);
    for (int i = 0; i < lim; i += 4) {
      int s0 = __shfl(ei, q16 + i);
      int s1 = __shfl(ei, q16 + i + 1);
      int s2 = __shfl(ei, q16 + i + 2);
      int s3 = __shfl(ei, q16 + i + 3);
      s0 = (i     < m) ? s0 : NN;                  // clamp to zero row
      s1 = (i + 1 < m) ? s1 : NN;
      s2 = (i + 2 < m) ? s2 : NN;
      s3 = (i + 3 < m) ? s3 : NN;
      u32x4 p0 = fv4[s0 * 16 + l15];
      u32x4 p1 = fv4[s1 * 16 + l15];
      u32x4 p2 = fv4[s2 * 16 + l15];
      u32x4 p3 = fv4[s3 * 16 + l15];
      ACC(p0); ACC(p1); ACC(p2); ACC(p3);
    }
  }

  const float inv = (c > 0) ? 1.0f / (float)c : 0.0f;
  u32x4 o;
  o.x = (u32)f2b(a0 * inv) | ((u32)f2b(a1 * inv) << 16);
  o.y = (u32)f2b(a2 * inv) | ((u32)f2b(a3 * inv) << 16);
  o.z = (u32)f2b(a4 * inv) | ((u32)f2b(a5 * inv) << 16);
  o.w = (u32)f2b(a6 * inv) | ((u32)f2b(a7 * inv) << 16);
  Mv4[seg * 16 + l15] = o;
}

// ---- fused GEMM: out = sum_r M_r @ W_r + f @ (W10+root), K = 11*128 ----
// B (wt_r, 32KB) staged in LDS per relation; pre-swizzled so ds_read_b128 is ~free.
__global__ __launch_bounds__(256) void gemm2_k(const u16* __restrict__ fbf,
                                               const u16* __restrict__ M,
                                               const u16* __restrict__ wt,
                                               float* __restrict__ out) {
  __shared__ __align__(16) u16 bs[128 * 128];      // 32 KB
  const int tid  = threadIdx.x;
  const int lane = tid & 63;
  const int wv   = tid >> 6;
  const int l15  = lane & 15;
  const int ko   = lane >> 4;                      // 0..3
  const int row  = blockIdx.x * 64 + wv * 16 + l15;
  const int rowc = (row < NN) ? row : 0;

  f32x4 acc[8];
#pragma unroll
  for (int i = 0; i < 8; ++i) acc[i] = (f32x4){0.f, 0.f, 0.f, 0.f};

  for (int r = 0; r < RT; ++r) {
    // stage wt_r -> LDS (linear vector copy; layout already swizzled)
    const bf16x8* wsrc = reinterpret_cast<const bf16x8*>(wt + (r << 14));
    bf16x8* ldst = reinterpret_cast<bf16x8*>(bs);
#pragma unroll
    for (int j = 0; j < 8; ++j) ldst[tid + j * 256] = wsrc[tid + j * 256];
    __syncthreads();

    const u16* arow = (r < 10) ? (M + ((long)r * NN + rowc) * FF)
                               : (fbf + (long)rowc * FF);
#pragma unroll
    for (int kc = 0; kc < 4; ++kc) {
      bf16x8 a = *reinterpret_cast<const bf16x8*>(arow + kc * 32 + ko * 8);
#pragma unroll
      for (int cf = 0; cf < 8; ++cf) {
        const int o = cf * 16 + l15;
        bf16x8 b = *reinterpret_cast<const bf16x8*>(
            &bs[(o << 7) + (((kc * 4 + ko) ^ (l15 & 7)) << 3)]);
        acc[cf] = __builtin_amdgcn_mfma_f32_16x16x32_bf16(a, b, acc[cf], 0, 0, 0);
      }
    }
    __syncthreads();
  }

  // store: D layout col=lane&15, row=(lane>>4)*4+reg
  const int rbase = blockIdx.x * 64 + wv * 16 + ko * 4;
#pragma unroll
  for (int cf = 0; cf < 8; ++cf)
#pragma unroll
    for (int q2 = 0; q2 < 4; ++q2) {
      int rd = rbase + q2;
      if (rd < NN) out[rd * FF + cf * 16 + l15] = acc[cf][q2];
    }
}

extern "C" void kernel_launch(void* const* d_in, const int* in_sizes, int n_in,
                              void* d_out, int out_size, void* d_ws, size_t ws_size,
                              hipStream_t stream) {
  const int*   graph  = (const int*)d_in[0];
  const float* feat   = (const float*)d_in[1];
  const float* weight = (const float*)d_in[2];
  const float* root   = (const float*)d_in[3];
  float* out = (float*)d_out;
  char* ws = (char*)d_ws;

  // workspace layout (256B-aligned), ~151.6 MB total:
  u16* fbf  = (u16*)(ws);                       // (NN+1)*128*2 = 12,800,256 (+pad)
  u16* wt   = (u16*)(ws + 12800512);            // 11*128*128*2 =    360,448
  int* cnt  = (int*)(ws + 13160960);            // NBINS*4      =  2,000,000 (counts -> local excl scan in place)
  int* cur  = (int*)(ws + 15160960);            // NBINS*4      =  2,000,000 (fill cursors == counts after fill)
  int* bsum = (int*)(ws + 17160960);            // NBLK*4 (pad) =      8,192
  int* eidx = (int*)(ws + 17169152);            // 2*EE*4       =  6,400,000
  u16* M    = (u16*)(ws + 23569152);            // 10*50000*128*2 = 128,000,000

  hipMemsetAsync(cnt, 0, NBINS * sizeof(int), stream);
  hipMemsetAsync(cur, 0, NBINS * sizeof(int), stream);
  prep_k<<<FEAT_BLKS + WT_BLKS + 1, 256, 0, stream>>>(feat, weight, root, fbf, wt);
  count_k<<<EE / 256, 256, 0, stream>>>(graph, cnt);
  scan1_k<<<NBLK, 256, 0, stream>>>(cnt, bsum);
  scan2_k<<<1, 256, 0, stream>>>(bsum);
  fill_k<<<EE2 / 256, 256, 0, stream>>>(graph, cnt, bsum, cur, eidx);
  // mean: cur=counts, cnt=scanned-local offsets
  mean_k<<<NBINS / 16, 256, 0, stream>>>(cur, cnt, bsum, eidx,
                                         (const u32x4*)fbf, (u32x4*)M);
  gemm2_k<<<(NN + 63) / 64, 256, 0, stream>>>(fbf, M, wt, out);
}

// Round 6
// 316.586 us; speedup vs baseline: 5.0598x; 1.1179x over previous
//
#include <hip/hip_runtime.h>
#include <hip/hip_bf16.h>

#define NN 50000      // nodes
#define RO 5          // original relations
#define RT 11         // total relations (2*RO+1)
#define FF 128        // feature dim (in == out)
#define EE 800000     // edges
#define NBINS (2 * RO * NN)          // 500000 segment bins (r<10)
#define SLOTS 32                     // fixed u16 slots per bin = one 64B line
#define FEAT_BLKS ((NN * FF / 4) / 256)   // 6250
#define WT_BLKS ((RT * FF * FF) / 256)    // 704

typedef unsigned short u16;
typedef unsigned int u32;
typedef __attribute__((ext_vector_type(4))) unsigned short u16x4;
typedef __attribute__((ext_vector_type(4))) unsigned int u32x4;
typedef __attribute__((ext_vector_type(8))) short bf16x8;   // 8 bf16 (4 VGPRs)
typedef __attribute__((ext_vector_type(4))) float f32x4;

// fp32 -> bf16 round-to-nearest-even
__device__ __forceinline__ u16 f2b(float x) {
  unsigned u = __float_as_uint(x);
  return (u16)((u + 0x7fffu + ((u >> 16) & 1u)) >> 16);
}

// ---- prep: cast features fp32->bf16 (+ zero row NN) + transpose/swizzle weights ----
// Weight layout: wt[r][o][chunk^(o&7)][k&7], chunk = k>>3 (16B-granular XOR swizzle
// so a LINEAR copy into LDS + swizzled ds_read_b128 is bank-conflict-free, rule 21).
__global__ __launch_bounds__(256) void prep_k(const float* __restrict__ f,
                                              const float* __restrict__ w,
                                              const float* __restrict__ root,
                                              u16* __restrict__ fb,
                                              u16* __restrict__ wt) {
  int b = blockIdx.x;
  if (b < FEAT_BLKS) {                             // features: 4 floats/thread
    int i = b * 256 + threadIdx.x;
    float4 v = reinterpret_cast<const float4*>(f)[i];
    u16x4 o;
    o.x = f2b(v.x); o.y = f2b(v.y); o.z = f2b(v.z); o.w = f2b(v.w);
    reinterpret_cast<u16x4*>(fb)[i] = o;
  } else if (b < FEAT_BLKS + WT_BLKS) {            // weights
    int idx = (b - FEAT_BLKS) * 256 + threadIdx.x; // r*16384 + k*128 + o
    int r = idx >> 14;
    int rem = idx & 16383;
    int k = rem >> 7;
    int o = rem & 127;
    float v = w[idx];
    if (r == 10) v += root[rem];
    int chunk = (k >> 3) ^ (o & 7);
    wt[(r << 14) + (o << 7) + (chunk << 3) + (k & 7)] = f2b(v);
  } else {                                         // zero row at index NN
    if (threadIdx.x < 64) reinterpret_cast<u32*>(fb)[NN * 64 + threadIdx.x] = 0;
  }
}

// ---- fill fixed-slot bins: 2 edges/thread -> 4 independent atomic chains ----
// eidx[bin*32 + pos] (u16): one bin == one 64B line -> line-local scatter.
__global__ __launch_bounds__(256) void fill_k(const int* __restrict__ g,
                                              int* __restrict__ cur,
                                              u16* __restrict__ eidx) {
  const int e0 = (blockIdx.x * 256 + threadIdx.x) * 2;
  if (e0 >= EE) return;
  int s0 = g[3 * e0], r0 = g[3 * e0 + 1], d0 = g[3 * e0 + 2];
  int b0f = r0 * NN + d0;
  int b0r = (r0 + RO) * NN + s0;
  int p0f = atomicAdd(&cur[b0f], 1);
  int p0r = atomicAdd(&cur[b0r], 1);
  if (p0f < SLOTS) eidx[b0f * SLOTS + p0f] = (u16)s0;
  if (p0r < SLOTS) eidx[b0r * SLOTS + p0r] = (u16)d0;
  const int e1 = e0 + 1;
  if (e1 >= EE) return;
  int s1 = g[3 * e1], r1 = g[3 * e1 + 1], d1 = g[3 * e1 + 2];
  int b1f = r1 * NN + d1;
  int b1r = (r1 + RO) * NN + s1;
  int p1f = atomicAdd(&cur[b1f], 1);
  int p1r = atomicAdd(&cur[b1r], 1);
  if (p1f < SLOTS) eidx[b1f * SLOTS + p1f] = (u16)s1;
  if (p1r < SLOTS) eidx[b1r * SLOTS + p1r] = (u16)d1;
}

#define ACC(p) { a0 += __uint_as_float((p).x << 16); a1 += __uint_as_float((p).x & 0xffff0000u); \
                 a2 += __uint_as_float((p).y << 16); a3 += __uint_as_float((p).y & 0xffff0000u); \
                 a4 += __uint_as_float((p).z << 16); a5 += __uint_as_float((p).z & 0xffff0000u); \
                 a6 += __uint_as_float((p).w << 16); a7 += __uint_as_float((p).w & 0xffff0000u); }

// ---- segment mean: each 16-lane quarter-wave owns one (r,dst) bin ----
// One u32 load per lane fetches the bin's 32 slots; shuffle-extract feeds
// 4 independent gather chains x 4-unroll. Invalid slots clamp to zero row NN.
__global__ __launch_bounds__(256) void mean_k(const int* __restrict__ cnt,
                                              const u32* __restrict__ eidx32,
                                              const u32x4* __restrict__ fv4,
                                              u32x4* __restrict__ Mv4) {
  const int lane = threadIdx.x & 63;
  const int wv   = threadIdx.x >> 6;
  const int q    = lane >> 4;
  const int l15  = lane & 15;
  const int q16  = q << 4;
  const int seg  = blockIdx.x * 16 + wv * 4 + q;   // grid exact: NBINS/16
  const int c    = min(cnt[seg], SLOTS);
  const u32 slots = eidx32[seg * 16 + l15];        // slots 2*l15, 2*l15+1

  int cmax = c;
  cmax = max(cmax, __shfl_xor(cmax, 16));
  cmax = max(cmax, __shfl_xor(cmax, 32));          // wave-uniform max count

  float a0 = 0.f, a1 = 0.f, a2 = 0.f, a3 = 0.f, a4 = 0.f, a5 = 0.f, a6 = 0.f, a7 = 0.f;

  for (int i = 0; i < cmax; i += 4) {
    u32 w0 = __shfl(slots, q16 + (i >> 1));        // slots i, i+1
    u32 w1 = __shfl(slots, q16 + (i >> 1) + 1);    // slots i+2, i+3
    int s0 = (i     < c) ? (int)(w0 & 0xffffu) : NN;
    int s1 = (i + 1 < c) ? (int)(w0 >> 16)     : NN;
    int s2 = (i + 2 < c) ? (int)(w1 & 0xffffu) : NN;
    int s3 = (i + 3 < c) ? (int)(w1 >> 16)     : NN;
    u32x4 p0 = fv4[s0 * 16 + l15];
    u32x4 p1 = fv4[s1 * 16 + l15];
    u32x4 p2 = fv4[s2 * 16 + l15];
    u32x4 p3 = fv4[s3 * 16 + l15];
    ACC(p0); ACC(p1); ACC(p2); ACC(p3);
  }

  const float inv = (c > 0) ? 1.0f / (float)c : 0.0f;
  u32x4 o;
  o.x = (u32)f2b(a0 * inv) | ((u32)f2b(a1 * inv) << 16);
  o.y = (u32)f2b(a2 * inv) | ((u32)f2b(a3 * inv) << 16);
  o.z = (u32)f2b(a4 * inv) | ((u32)f2b(a5 * inv) << 16);
  o.w = (u32)f2b(a6 * inv) | ((u32)f2b(a7 * inv) << 16);
  Mv4[seg * 16 + l15] = o;
}

// ---- fused GEMM: out = sum_r M_r @ W_r + f @ (W10+root), K = 11*128 ----
// B (wt_r, 32KB) staged in LDS per relation; pre-swizzled so ds_read_b128 is ~free.
__global__ __launch_bounds__(256) void gemm2_k(const u16* __restrict__ fbf,
                                               const u16* __restrict__ M,
                                               const u16* __restrict__ wt,
                                               float* __restrict__ out) {
  __shared__ __align__(16) u16 bs[128 * 128];      // 32 KB
  const int tid  = threadIdx.x;
  const int lane = tid & 63;
  const int wv   = tid >> 6;
  const int l15  = lane & 15;
  const int ko   = lane >> 4;                      // 0..3
  const int row  = blockIdx.x * 64 + wv * 16 + l15;
  const int rowc = (row < NN) ? row : 0;

  f32x4 acc[8];
#pragma unroll
  for (int i = 0; i < 8; ++i) acc[i] = (f32x4){0.f, 0.f, 0.f, 0.f};

  for (int r = 0; r < RT; ++r) {
    // stage wt_r -> LDS (linear vector copy; layout already swizzled)
    const bf16x8* wsrc = reinterpret_cast<const bf16x8*>(wt + (r << 14));
    bf16x8* ldst = reinterpret_cast<bf16x8*>(bs);
#pragma unroll
    for (int j = 0; j < 8; ++j) ldst[tid + j * 256] = wsrc[tid + j * 256];
    __syncthreads();

    const u16* arow = (r < 10) ? (M + ((long)r * NN + rowc) * FF)
                               : (fbf + (long)rowc * FF);
#pragma unroll
    for (int kc = 0; kc < 4; ++kc) {
      bf16x8 a = *reinterpret_cast<const bf16x8*>(arow + kc * 32 + ko * 8);
#pragma unroll
      for (int cf = 0; cf < 8; ++cf) {
        const int o = cf * 16 + l15;
        bf16x8 b = *reinterpret_cast<const bf16x8*>(
            &bs[(o << 7) + (((kc * 4 + ko) ^ (l15 & 7)) << 3)]);
        acc[cf] = __builtin_amdgcn_mfma_f32_16x16x32_bf16(a, b, acc[cf], 0, 0, 0);
      }
    }
    __syncthreads();
  }

  // store: D layout col=lane&15, row=(lane>>4)*4+reg
  const int rbase = blockIdx.x * 64 + wv * 16 + ko * 4;
#pragma unroll
  for (int cf = 0; cf < 8; ++cf)
#pragma unroll
    for (int q2 = 0; q2 < 4; ++q2) {
      int rd = rbase + q2;
      if (rd < NN) out[rd * FF + cf * 16 + l15] = acc[cf][q2];
    }
}

extern "C" void kernel_launch(void* const* d_in, const int* in_sizes, int n_in,
                              void* d_out, int out_size, void* d_ws, size_t ws_size,
                              hipStream_t stream) {
  const int*   graph  = (const int*)d_in[0];
  const float* feat   = (const float*)d_in[1];
  const float* weight = (const float*)d_in[2];
  const float* root   = (const float*)d_in[3];
  float* out = (float*)d_out;
  char* ws = (char*)d_ws;

  // workspace layout (256B-aligned), ~175 MB total:
  u16* fbf  = (u16*)(ws);                       // (NN+1)*128*2 = 12,800,256 (+pad)
  u16* wt   = (u16*)(ws + 12800512);            // 11*128*128*2 =    360,448
  int* cur  = (int*)(ws + 13160960);            // NBINS*4      =  2,000,000 (+pad) fill cursors == counts
  u16* eidx = (u16*)(ws + 15161088);            // NBINS*32*2   = 32,000,000 fixed-slot bins
  u16* M    = (u16*)(ws + 47161088);            // 10*50000*128*2 = 128,000,000

  hipMemsetAsync(cur, 0, NBINS * sizeof(int), stream);
  prep_k<<<FEAT_BLKS + WT_BLKS + 1, 256, 0, stream>>>(feat, weight, root, fbf, wt);
  fill_k<<<(EE / 2 + 255) / 256, 256, 0, stream>>>(graph, cur, eidx);
  mean_k<<<NBINS / 16, 256, 0, stream>>>(cur, (const u32*)eidx,
                                         (const u32x4*)fbf, (u32x4*)M);
  gemm2_k<<<(NN + 63) / 64, 256, 0, stream>>>(fbf, M, wt, out);
}

// Round 9
// 288.103 us; speedup vs baseline: 5.5600x; 1.0989x over previous
//
#include <hip/hip_runtime.h>
#include <hip/hip_bf16.h>

#define NN 50000      // nodes
#define RO 5          // original relations
#define RT 11         // total relations (2*RO+1)
#define FF 128        // feature dim (in == out)
#define EE 800000     // edges
#define EE2 (2 * EE)
#define NBINS (2 * RO * NN)          // 500000 segment bins (r<10)
#define SLOTS 32                     // fixed u16 slots per bin = one 64B line
#define DPB 32                       // dst rows per block in fused kernel
#define FEAT_BLKS ((NN * FF / 4) / 256)   // 6250
#define WT_BLKS ((RT * FF * FF) / 256)    // 704

typedef unsigned short u16;
typedef unsigned int u32;
typedef __attribute__((ext_vector_type(4))) unsigned short u16x4;
typedef __attribute__((ext_vector_type(4))) unsigned int u32x4;
typedef __attribute__((ext_vector_type(8))) short bf16x8;   // 8 bf16 (4 VGPRs)
typedef __attribute__((ext_vector_type(4))) float f32x4;

// fp32 -> bf16 round-to-nearest-even
__device__ __forceinline__ u16 f2b(float x) {
  unsigned u = __float_as_uint(x);
  return (u16)((u + 0x7fffu + ((u >> 16) & 1u)) >> 16);
}

// ---- prep: cast features fp32->bf16 (+ zero row NN) + transpose/swizzle weights ----
// Weight layout: wt[r][o][chunk^(o&7)][k&7], chunk = k>>3 (16B-granular XOR swizzle;
// same involution used on every read side, rule 21).
__global__ __launch_bounds__(256) void prep_k(const float* __restrict__ f,
                                              const float* __restrict__ w,
                                              const float* __restrict__ root,
                                              u16* __restrict__ fb,
                                              u16* __restrict__ wt) {
  int b = blockIdx.x;
  if (b < FEAT_BLKS) {                             // features: 4 floats/thread
    int i = b * 256 + threadIdx.x;
    float4 v = reinterpret_cast<const float4*>(f)[i];
    u16x4 o;
    o.x = f2b(v.x); o.y = f2b(v.y); o.z = f2b(v.z); o.w = f2b(v.w);
    reinterpret_cast<u16x4*>(fb)[i] = o;
  } else if (b < FEAT_BLKS + WT_BLKS) {            // weights
    int idx = (b - FEAT_BLKS) * 256 + threadIdx.x; // r*16384 + k*128 + o
    int r = idx >> 14;
    int rem = idx & 16383;
    int k = rem >> 7;
    int o = rem & 127;
    float v = w[idx];
    if (r == 10) v += root[rem];
    int chunk = (k >> 3) ^ (o & 7);
    wt[(r << 14) + (o << 7) + (chunk << 3) + (k & 7)] = f2b(v);
  } else {                                         // zero row at index NN
    if (threadIdx.x < 64) reinterpret_cast<u32*>(fb)[NN * 64 + threadIdx.x] = 0;
  }
}

// ---- fill fixed-slot bins: 1 MESSAGE per thread (max TLP; R5-proven layout) ----
__global__ __launch_bounds__(256) void fill_k(const int* __restrict__ g,
                                              int* __restrict__ cur,
                                              u16* __restrict__ eidx) {
  const int m = blockIdx.x * 256 + threadIdx.x;    // grid exact: EE2/256
  int e, bin; u16 val;
  if (m < EE) {
    e = m;
    int s = g[3 * e], r = g[3 * e + 1], d = g[3 * e + 2];
    bin = r * NN + d; val = (u16)s;                // forward: rel, dst <- src
  } else {
    e = m - EE;
    int d2 = g[3 * e], r = g[3 * e + 1], s2 = g[3 * e + 2];
    bin = (r + RO) * NN + d2; val = (u16)s2;       // reversed: rel+RO, src <- dst
  }
  int pos = atomicAdd(&cur[bin], 1);
  if (pos < SLOTS) eidx[bin * SLOTS + pos] = val;
}

#define ACCX(p) { a0 += __uint_as_float((p).x << 16); a1 += __uint_as_float((p).x & 0xffff0000u); \
                  a2 += __uint_as_float((p).y << 16); a3 += __uint_as_float((p).y & 0xffff0000u); \
                  a4 += __uint_as_float((p).z << 16); a5 += __uint_as_float((p).z & 0xffff0000u); \
                  a6 += __uint_as_float((p).w << 16); a7 += __uint_as_float((p).w & 0xffff0000u); }
#define ACCY(p) { b0 += __uint_as_float((p).x << 16); b1 += __uint_as_float((p).x & 0xffff0000u); \
                  b2 += __uint_as_float((p).y << 16); b3 += __uint_as_float((p).y & 0xffff0000u); \
                  b4 += __uint_as_float((p).z << 16); b5 += __uint_as_float((p).z & 0xffff0000u); \
                  b6 += __uint_as_float((p).w << 16); b7 += __uint_as_float((p).w & 0xffff0000u); }

// ---- fused segment-mean + GEMM: out = sum_r mean_r @ W_r + f @ (W10+root) ----
// Block owns DPB=32 dst rows. Per relation: 16 quarter-waves each compute 2 mean
// rows (2 chains x 4-unroll = 8 gathers in flight), write the 32x128 tile into
// swizzled LDS, then 4 waves MFMA it against Wr (B frags from L2-hot wt).
// M buffer eliminated entirely.
__global__ __launch_bounds__(256) void mg_k(const int* __restrict__ cnt,
                                            const u32* __restrict__ eidx32,
                                            const u32x4* __restrict__ fv4,
                                            const u16* __restrict__ fbf,
                                            const u16* __restrict__ wt,
                                            float* __restrict__ out) {
  __shared__ __align__(16) u32x4 Asw[DPB * 16];    // 8 KB swizzled A tile
  const int tid  = threadIdx.x;
  const int lane = tid & 63;
  const int wv   = tid >> 6;
  const int l15  = lane & 15;
  const int ko   = lane >> 4;                      // quarter id within wave (== k-subchunk)
  const int qid  = wv * 4 + ko;                    // 0..15
  const int q16  = ko << 4;
  const int base = blockIdx.x * DPB;

  f32x4 acc[2][2];
#pragma unroll
  for (int i = 0; i < 2; ++i)
#pragma unroll
    for (int j = 0; j < 2; ++j) acc[i][j] = (f32x4){0.f, 0.f, 0.f, 0.f};

  const int row0 = qid * 2, row1 = row0 + 1;
  const int d0 = base + row0, d1 = base + row1;
  const bool v0 = d0 < NN, v1 = d1 < NN;

  for (int r = 0; r < 10; ++r) {
    // ---- mean of 2 segments per quarter-wave ----
    const int seg0 = v0 ? r * NN + d0 : 0;
    const int seg1 = v1 ? r * NN + d1 : 0;
    const int c0 = v0 ? min(cnt[seg0], SLOTS) : 0;
    const int c1 = v1 ? min(cnt[seg1], SLOTS) : 0;
    const u32 sl0 = eidx32[seg0 * 16 + l15];       // slots 2*l15, 2*l15+1
    const u32 sl1 = eidx32[seg1 * 16 + l15];
    int cmax = max(c0, c1);
    cmax = max(cmax, __shfl_xor(cmax, 16));
    cmax = max(cmax, __shfl_xor(cmax, 32));        // wave-uniform

    float a0 = 0.f, a1 = 0.f, a2 = 0.f, a3 = 0.f, a4 = 0.f, a5 = 0.f, a6 = 0.f, a7 = 0.f;
    float b0 = 0.f, b1 = 0.f, b2 = 0.f, b3 = 0.f, b4 = 0.f, b5 = 0.f, b6 = 0.f, b7 = 0.f;

    for (int i = 0; i < cmax; i += 4) {
      u32 wa0 = __shfl(sl0, q16 + (i >> 1));
      u32 wa1 = __shfl(sl0, q16 + (i >> 1) + 1);
      u32 wb0 = __shfl(sl1, q16 + (i >> 1));
      u32 wb1 = __shfl(sl1, q16 + (i >> 1) + 1);
      int s0 = (i     < c0) ? (int)(wa0 & 0xffffu) : NN;
      int s1 = (i + 1 < c0) ? (int)(wa0 >> 16)     : NN;
      int s2 = (i + 2 < c0) ? (int)(wa1 & 0xffffu) : NN;
      int s3 = (i + 3 < c0) ? (int)(wa1 >> 16)     : NN;
      int t0 = (i     < c1) ? (int)(wb0 & 0xffffu) : NN;
      int t1 = (i + 1 < c1) ? (int)(wb0 >> 16)     : NN;
      int t2 = (i + 2 < c1) ? (int)(wb1 & 0xffffu) : NN;
      int t3 = (i + 3 < c1) ? (int)(wb1 >> 16)     : NN;
      u32x4 p0 = fv4[s0 * 16 + l15];
      u32x4 p1 = fv4[s1 * 16 + l15];
      u32x4 p2 = fv4[s2 * 16 + l15];
      u32x4 p3 = fv4[s3 * 16 + l15];
      u32x4 p4 = fv4[t0 * 16 + l15];
      u32x4 p5 = fv4[t1 * 16 + l15];
      u32x4 p6 = fv4[t2 * 16 + l15];
      u32x4 p7 = fv4[t3 * 16 + l15];
      ACCX(p0); ACCX(p1); ACCX(p2); ACCX(p3);
      ACCY(p4); ACCY(p5); ACCY(p6); ACCY(p7);
    }

    const float i0 = (c0 > 0) ? 1.0f / (float)c0 : 0.0f;
    const float i1 = (c1 > 0) ? 1.0f / (float)c1 : 0.0f;
    u32x4 m0, m1;
    m0.x = (u32)f2b(a0 * i0) | ((u32)f2b(a1 * i0) << 16);
    m0.y = (u32)f2b(a2 * i0) | ((u32)f2b(a3 * i0) << 16);
    m0.z = (u32)f2b(a4 * i0) | ((u32)f2b(a5 * i0) << 16);
    m0.w = (u32)f2b(a6 * i0) | ((u32)f2b(a7 * i0) << 16);
    m1.x = (u32)f2b(b0 * i1) | ((u32)f2b(b1 * i1) << 16);
    m1.y = (u32)f2b(b2 * i1) | ((u32)f2b(b3 * i1) << 16);
    m1.z = (u32)f2b(b4 * i1) | ((u32)f2b(b5 * i1) << 16);
    m1.w = (u32)f2b(b6 * i1) | ((u32)f2b(b7 * i1) << 16);
    Asw[row0 * 16 + (l15 ^ (row0 & 7))] = m0;      // swizzled write (rule 21:
    Asw[row1 * 16 + (l15 ^ (row1 & 7))] = m1;      //  same XOR on read side)
    __syncthreads();

    // ---- MFMA: C[32 x 32cols] += A(32x128) @ Wr(128x32) ----
    const u16* wb = wt + (r << 14);
#pragma unroll
    for (int kc = 0; kc < 4; ++kc) {
      bf16x8 afr[2];
#pragma unroll
      for (int fq = 0; fq < 2; ++fq) {
        const int arow = fq * 16 + l15;
        afr[fq] = *reinterpret_cast<const bf16x8*>(
            &Asw[arow * 16 + ((kc * 4 + ko) ^ (arow & 7))]);
      }
#pragma unroll
      for (int fr = 0; fr < 2; ++fr) {
        const int o = wv * 32 + fr * 16 + l15;     // o&7 == l15&7
        bf16x8 b = *reinterpret_cast<const bf16x8*>(
            wb + (o << 7) + (((kc * 4 + ko) ^ (o & 7)) << 3));
        acc[0][fr] = __builtin_amdgcn_mfma_f32_16x16x32_bf16(afr[0], b, acc[0][fr], 0, 0, 0);
        acc[1][fr] = __builtin_amdgcn_mfma_f32_16x16x32_bf16(afr[1], b, acc[1][fr], 0, 0, 0);
      }
    }
    __syncthreads();
  }

  // ---- r == 10: A = features (root folded into Wt[10]) ----
  {
    const u16* wb = wt + (10 << 14);
#pragma unroll
    for (int kc = 0; kc < 4; ++kc) {
      bf16x8 afr[2];
#pragma unroll
      for (int fq = 0; fq < 2; ++fq) {
        int rowg = base + fq * 16 + l15;
        rowg = (rowg < NN) ? rowg : NN;            // zero row for OOB
        afr[fq] = *reinterpret_cast<const bf16x8*>(
            fbf + (long)rowg * FF + kc * 32 + ko * 8);
      }
#pragma unroll
      for (int fr = 0; fr < 2; ++fr) {
        const int o = wv * 32 + fr * 16 + l15;
        bf16x8 b = *reinterpret_cast<const bf16x8*>(
            wb + (o << 7) + (((kc * 4 + ko) ^ (o & 7)) << 3));
        acc[0][fr] = __builtin_amdgcn_mfma_f32_16x16x32_bf16(afr[0], b, acc[0][fr], 0, 0, 0);
        acc[1][fr] = __builtin_amdgcn_mfma_f32_16x16x32_bf16(afr[1], b, acc[1][fr], 0, 0, 0);
      }
    }
  }

  // ---- store: D layout col=lane&15, row=(lane>>4)*4+reg ----
#pragma unroll
  for (int fq = 0; fq < 2; ++fq)
#pragma unroll
    for (int fr = 0; fr < 2; ++fr)
#pragma unroll
      for (int q2 = 0; q2 < 4; ++q2) {
        const int row = base + fq * 16 + ko * 4 + q2;
        if (row < NN) out[row * FF + wv * 32 + fr * 16 + l15] = acc[fq][fr][q2];
      }
}

extern "C" void kernel_launch(void* const* d_in, const int* in_sizes, int n_in,
                              void* d_out, int out_size, void* d_ws, size_t ws_size,
                              hipStream_t stream) {
  const int*   graph  = (const int*)d_in[0];
  const float* feat   = (const float*)d_in[1];
  const float* weight = (const float*)d_in[2];
  const float* root   = (const float*)d_in[3];
  float* out = (float*)d_out;
  char* ws = (char*)d_ws;

  // workspace layout (256B-aligned), ~47 MB total:
  u16* fbf  = (u16*)(ws);                       // (NN+1)*128*2 = 12,800,256 (+pad)
  u16* wt   = (u16*)(ws + 12800512);            // 11*128*128*2 =    360,448
  int* cur  = (int*)(ws + 13160960);            // NBINS*4      =  2,000,000 (+pad)
  u16* eidx = (u16*)(ws + 15161088);            // NBINS*32*2   = 32,000,000

  hipMemsetAsync(cur, 0, NBINS * sizeof(int), stream);
  prep_k<<<FEAT_BLKS + WT_BLKS + 1, 256, 0, stream>>>(feat, weight, root, fbf, wt);
  fill_k<<<EE2 / 256, 256, 0, stream>>>(graph, cur, eidx);
  mg_k<<<(NN + DPB - 1) / DPB, 256, 0, stream>>>(cur, (const u32*)eidx,
                                                 (const u32x4*)fbf, fbf, wt, out);
}